// Round 1
// baseline (1149.507 us; speedup 1.0000x reference)
//
#include <hip/hip_runtime.h>

typedef unsigned int u32;
typedef unsigned short u16;
typedef __attribute__((ext_vector_type(4))) float floatx4;
typedef __attribute__((ext_vector_type(8))) __bf16 bf16x8;

#define T_ 2048
#define D_ 2048
#define DL_ 1024
#define E_ 64
#define I_ 768
#define SI_ 4096
#define TOPK 6
#define NGRP 8
#define TOPG 4
#define CAP_ 384

#define BM 128
#define BN 128
#define BK 32
#define LDS_PAD 40

__device__ __forceinline__ u16 f2bf(float f) {
  u32 u = __builtin_bit_cast(u32, f);
  u += 0x7fffu + ((u >> 16) & 1u);  // RNE to bf16 (finite data, no NaN handling)
  return (u16)(u >> 16);
}
__device__ __forceinline__ float bf2f(u16 h) {
  return __builtin_bit_cast(float, ((u32)h) << 16);
}

// ---------------- gate logits: [T,E] = x @ gate_w^T in fp32 ----------------
__global__ __launch_bounds__(256) void gate_logits_k(const float* __restrict__ x,
                                                     const float* __restrict__ gw,
                                                     float* __restrict__ logits) {
  __shared__ float xs[16 * 65];
  __shared__ float wsd[64 * 65];
  const int tid = threadIdx.x;
  const int t0 = blockIdx.x * 16;
  const int tl = tid & 15, eb = (tid >> 4) * 4;
  const int xr = tid >> 4, xc = (tid & 15) * 4;
  const int wr = tid >> 2, wc = (tid & 3) * 16;
  float acc[4] = {0.f, 0.f, 0.f, 0.f};
  for (int kc = 0; kc < D_; kc += 64) {
    __syncthreads();
    float4 xv = *(const float4*)&x[(size_t)(t0 + xr) * D_ + kc + xc];
    xs[xr * 65 + xc + 0] = xv.x;
    xs[xr * 65 + xc + 1] = xv.y;
    xs[xr * 65 + xc + 2] = xv.z;
    xs[xr * 65 + xc + 3] = xv.w;
#pragma unroll
    for (int i = 0; i < 4; ++i) {
      float4 wv = *(const float4*)&gw[(size_t)wr * D_ + kc + wc + i * 4];
      wsd[wr * 65 + wc + i * 4 + 0] = wv.x;
      wsd[wr * 65 + wc + i * 4 + 1] = wv.y;
      wsd[wr * 65 + wc + i * 4 + 2] = wv.z;
      wsd[wr * 65 + wc + i * 4 + 3] = wv.w;
    }
    __syncthreads();
#pragma unroll 4
    for (int kk = 0; kk < 64; ++kk) {
      float xvv = xs[tl * 65 + kk];
#pragma unroll
      for (int q = 0; q < 4; ++q) acc[q] += xvv * wsd[(eb + q) * 65 + kk];
    }
  }
#pragma unroll
  for (int q = 0; q < 4; ++q) logits[(size_t)(t0 + tl) * E_ + eb + q] = acc[q];
}

// ---------------- routing: sigmoid + bias, group top-2 sum, top-4 groups, top-6 experts ----------------
__global__ __launch_bounds__(256) void route_k(const float* __restrict__ logits,
                                               const float* __restrict__ bias,
                                               int* __restrict__ cnts,
                                               int* __restrict__ etok,
                                               int* __restrict__ row_of,
                                               float* __restrict__ tww) {
  int t = blockIdx.x * 256 + threadIdx.x;
  if (t >= T_) return;
  float s[E_], cand[E_];
  float gs[NGRP];
  for (int e = 0; e < E_; ++e) {
    float lg = logits[(size_t)t * E_ + e];
    float sv = 1.f / (1.f + __expf(-lg));
    s[e] = sv;
    cand[e] = sv + bias[e];
  }
  for (int g = 0; g < NGRP; ++g) {
    float m1 = -1e30f, m2 = -1e30f;
    for (int j = 0; j < 8; ++j) {
      float v = cand[g * 8 + j];
      if (v > m1) { m2 = m1; m1 = v; }
      else if (v > m2) m2 = v;
    }
    gs[g] = m1 + m2;
  }
  bool gsel[NGRP];
  for (int g = 0; g < NGRP; ++g) gsel[g] = false;
  for (int r = 0; r < TOPG; ++r) {
    float best = -1e30f; int bi = 0;
    for (int g = 0; g < NGRP; ++g)
      if (!gsel[g] && gs[g] > best) { best = gs[g]; bi = g; }
    gsel[bi] = true;
  }
  for (int e = 0; e < E_; ++e)
    if (!gsel[e >> 3]) cand[e] = 0.0f;  // matches reference: masked scores become 0.0
  float wsum = 0.f; int eid[TOPK]; float wv[TOPK];
  for (int r = 0; r < TOPK; ++r) {
    float best = -1e30f; int bi = 0;
    for (int e = 0; e < E_; ++e)
      if (cand[e] > best) { best = cand[e]; bi = e; }
    cand[bi] = -1e30f;
    eid[r] = bi; wv[r] = s[bi]; wsum += s[bi];
  }
  float inv = 2.5f / (wsum + 1e-20f);
  for (int r = 0; r < TOPK; ++r) {
    int e = eid[r];
    int slot = atomicAdd(&cnts[e], 1);
    int rowid = -1;
    if (slot < CAP_) { rowid = e * CAP_ + slot; etok[rowid] = t; }
    row_of[t * TOPK + r] = rowid;
    tww[t * TOPK + r] = wv[r] * inv;
  }
}

// ---------------- generic NT GEMM: C[M,N] = A[M,K] * B[N,K]^T, bf16 MFMA ----------------
// ATYPE: 0 = A fp32 (convert to bf16 while staging), 1 = A bf16
// EPI:   0 = store bf16, 1 = relu^2 then store bf16, 2 = store fp32, 3 = accumulate fp32
template <int ATYPE, int EPI>
__global__ __launch_bounds__(256, 2) void gemm_nt(const void* __restrict__ Ap,
                                                  const float* __restrict__ Bp,
                                                  void* __restrict__ Cp,
                                                  int M, int K, int ldA, int ldB, int ldC,
                                                  long sAe, long sBe, long sCe,
                                                  const int* __restrict__ counts,
                                                  const int* __restrict__ gather) {
  __shared__ u16 As[BM * LDS_PAD];
  __shared__ u16 Bs[BN * LDS_PAD];
  const int e = blockIdx.z;
  int Mloc = M;
  if (counts) { Mloc = counts[e]; if (Mloc > CAP_) Mloc = CAP_; }
  const int m0 = blockIdx.y * BM;
  if (m0 >= Mloc) return;
  const int n0 = blockIdx.x * BN;
  const int tid = threadIdx.x;
  const int row = tid >> 1;
  const int colb = (tid & 1) * 16;

  const int arow = m0 + row;
  int arowIdx;
  if (gather) arowIdx = (arow < Mloc) ? gather[e * CAP_ + arow] : 0;
  else arowIdx = arow;

  const float* Af32 = (const float*)Ap + (size_t)e * sAe + (size_t)arowIdx * ldA;
  const u16* Abf = (const u16*)Ap + (size_t)e * sAe + (size_t)arowIdx * ldA;
  const float* Brow = Bp + (size_t)e * sBe + (size_t)(n0 + row) * ldB;

  float4 ra[4]; uint4 rab[2]; float4 rb[4];
  auto loadAB = [&](int kt) {
    if constexpr (ATYPE == 0) {
#pragma unroll
      for (int i = 0; i < 4; ++i) ra[i] = *(const float4*)&Af32[kt + colb + i * 4];
    } else {
#pragma unroll
      for (int i = 0; i < 2; ++i) rab[i] = *(const uint4*)&Abf[kt + colb + i * 8];
    }
#pragma unroll
    for (int i = 0; i < 4; ++i) rb[i] = *(const float4*)&Brow[kt + colb + i * 4];
  };
  auto stage = [&]() {
    uint4* ad = (uint4*)&As[row * LDS_PAD + colb];
    if constexpr (ATYPE == 0) {
      u32 w[8];
#pragma unroll
      for (int i = 0; i < 4; ++i) {
        w[2 * i] = (u32)f2bf(ra[i].x) | ((u32)f2bf(ra[i].y) << 16);
        w[2 * i + 1] = (u32)f2bf(ra[i].z) | ((u32)f2bf(ra[i].w) << 16);
      }
      ad[0] = make_uint4(w[0], w[1], w[2], w[3]);
      ad[1] = make_uint4(w[4], w[5], w[6], w[7]);
    } else {
      ad[0] = rab[0]; ad[1] = rab[1];
    }
    u32 wb[8];
#pragma unroll
    for (int i = 0; i < 4; ++i) {
      wb[2 * i] = (u32)f2bf(rb[i].x) | ((u32)f2bf(rb[i].y) << 16);
      wb[2 * i + 1] = (u32)f2bf(rb[i].z) | ((u32)f2bf(rb[i].w) << 16);
    }
    uint4* bd = (uint4*)&Bs[row * LDS_PAD + colb];
    bd[0] = make_uint4(wb[0], wb[1], wb[2], wb[3]);
    bd[1] = make_uint4(wb[4], wb[5], wb[6], wb[7]);
  };

  floatx4 acc[4][4];
#pragma unroll
  for (int i = 0; i < 4; ++i)
#pragma unroll
    for (int j = 0; j < 4; ++j) acc[i][j] = floatx4{0.f, 0.f, 0.f, 0.f};

  const int wave = tid >> 6, lane = tid & 63;
  const int wm = (wave & 1) * 64, wn = (wave >> 1) * 64;
  const int lr = lane & 15, lk = (lane >> 4) * 8;

  loadAB(0);
  for (int kt = 0; kt < K; kt += BK) {
    __syncthreads();
    stage();
    __syncthreads();
    if (kt + BK < K) loadAB(kt + BK);
    bf16x8 af[4], bfr[4];
#pragma unroll
    for (int i = 0; i < 4; ++i)
      af[i] = *(const bf16x8*)&As[(wm + i * 16 + lr) * LDS_PAD + lk];
#pragma unroll
    for (int j = 0; j < 4; ++j)
      bfr[j] = *(const bf16x8*)&Bs[(wn + j * 16 + lr) * LDS_PAD + lk];
#pragma unroll
    for (int i = 0; i < 4; ++i)
#pragma unroll
      for (int j = 0; j < 4; ++j)
        acc[i][j] = __builtin_amdgcn_mfma_f32_16x16x32_bf16(af[i], bfr[j], acc[i][j], 0, 0, 0);
  }

  const int rbase = (lane >> 4) * 4;
#pragma unroll
  for (int i = 0; i < 4; ++i) {
#pragma unroll
    for (int r = 0; r < 4; ++r) {
      int grow = m0 + wm + i * 16 + rbase + r;
      if (grow >= Mloc) continue;
      size_t crow = (size_t)sCe * e + (size_t)grow * ldC;
#pragma unroll
      for (int j = 0; j < 4; ++j) {
        int gcol = n0 + wn + j * 16 + lr;
        float v = acc[i][j][r];
        if constexpr (EPI == 0) {
          ((u16*)Cp)[crow + gcol] = f2bf(v);
        } else if constexpr (EPI == 1) {
          v = fmaxf(v, 0.f); v *= v;
          ((u16*)Cp)[crow + gcol] = f2bf(v);
        } else if constexpr (EPI == 2) {
          ((float*)Cp)[crow + gcol] = v;
        } else {
          ((float*)Cp)[crow + gcol] += v;
        }
      }
    }
  }
}

// ---------------- combine: ylat[t] = sum_k tw[t,k] * eout[row_of[t,k]] ----------------
__global__ __launch_bounds__(256) void combine_k(const u16* __restrict__ eout,
                                                 const int* __restrict__ row_of,
                                                 const float* __restrict__ tww,
                                                 u16* __restrict__ ylat) {
  int t = blockIdx.x;
  int c0 = threadIdx.x * 4;
  float a0 = 0.f, a1 = 0.f, a2 = 0.f, a3 = 0.f;
#pragma unroll
  for (int k = 0; k < TOPK; ++k) {
    int r = row_of[t * TOPK + k];
    float w = tww[t * TOPK + k];
    if (r >= 0) {
      uint2 v = *(const uint2*)&eout[(size_t)r * DL_ + c0];
      a0 += w * bf2f((u16)(v.x & 0xffffu));
      a1 += w * bf2f((u16)(v.x >> 16));
      a2 += w * bf2f((u16)(v.y & 0xffffu));
      a3 += w * bf2f((u16)(v.y >> 16));
    }
  }
  u32 o0 = (u32)f2bf(a0) | ((u32)f2bf(a1) << 16);
  u32 o1 = (u32)f2bf(a2) | ((u32)f2bf(a3) << 16);
  *(uint2*)&ylat[(size_t)t * DL_ + c0] = make_uint2(o0, o1);
}

extern "C" void kernel_launch(void* const* d_in, const int* in_sizes, int n_in,
                              void* d_out, int out_size, void* d_ws, size_t ws_size,
                              hipStream_t stream) {
  (void)in_sizes; (void)n_in; (void)out_size; (void)ws_size;
  const float* x = (const float*)d_in[0];
  const float* gw = (const float*)d_in[1];
  const float* gbias = (const float*)d_in[2];
  const float* fc1 = (const float*)d_in[3];
  const float* fc2 = (const float*)d_in[4];
  const float* w1 = (const float*)d_in[5];
  const float* w2 = (const float*)d_in[6];
  const float* sw1 = (const float*)d_in[7];
  const float* sw2 = (const float*)d_in[8];
  float* out = (float*)d_out;

  char* ws = (char*)d_ws;
  size_t off = 0;
  auto alloc = [&](size_t bytes) {
    char* p = ws + off;
    off += (bytes + 255) & ~(size_t)255;
    return p;
  };
  float* logits = (float*)alloc((size_t)T_ * E_ * 4);
  int* cnts = (int*)alloc(E_ * 4);
  int* etok = (int*)alloc((size_t)E_ * CAP_ * 4);
  int* row_of = (int*)alloc((size_t)T_ * TOPK * 4);
  float* tww = (float*)alloc((size_t)T_ * TOPK * 4);
  u16* xl = (u16*)alloc((size_t)T_ * DL_ * 2);
  u16* ylat = (u16*)alloc((size_t)T_ * DL_ * 2);
  char* big = alloc((size_t)E_ * CAP_ * I_ * 2 + (size_t)E_ * CAP_ * DL_ * 2);
  u16* hs = (u16*)big;                                  // [T,SI] bf16, used only in shared path
  u16* h = (u16*)big;                                   // [E*CAP,I] bf16, reuses hs space after
  u16* eoutB = (u16*)(big + (size_t)E_ * CAP_ * I_ * 2);  // [E*CAP,DL] bf16

  hipMemsetAsync(cnts, 0, E_ * 4, stream);
  gate_logits_k<<<T_ / 16, 256, 0, stream>>>(x, gw, logits);
  route_k<<<T_ / 256, 256, 0, stream>>>(logits, gbias, cnts, etok, row_of, tww);

  // shared path: hs = relu2(x @ sw1^T) ; out = hs @ sw2^T
  gemm_nt<0, 1><<<dim3(SI_ / BN, T_ / BM, 1), 256, 0, stream>>>(
      x, sw1, hs, T_, D_, D_, D_, SI_, 0, 0, 0, nullptr, nullptr);
  gemm_nt<1, 2><<<dim3(D_ / BN, T_ / BM, 1), 256, 0, stream>>>(
      hs, sw2, out, T_, SI_, SI_, SI_, D_, 0, 0, 0, nullptr, nullptr);

  // latent projection: xl = x @ fc1^T (bf16)
  gemm_nt<0, 0><<<dim3(DL_ / BN, T_ / BM, 1), 256, 0, stream>>>(
      x, fc1, xl, T_, D_, D_, D_, DL_, 0, 0, 0, nullptr, nullptr);

  // expert FFN stage 1: h = relu2(gather(xl) @ w1[e]^T)
  gemm_nt<1, 1><<<dim3(I_ / BN, CAP_ / BM, E_), 256, 0, stream>>>(
      xl, w1, h, CAP_, DL_, DL_, DL_, I_,
      0, (long)I_ * DL_, (long)CAP_ * I_, cnts, etok);

  // expert FFN stage 2: eout = h @ w2[e]^T
  gemm_nt<1, 0><<<dim3(DL_ / BN, CAP_ / BM, E_), 256, 0, stream>>>(
      h, w2, eoutB, CAP_, I_, I_, I_, DL_,
      (long)CAP_ * I_, (long)DL_ * I_, (long)CAP_ * DL_, cnts, nullptr);

  // combine with routing weights -> ylat (bf16)
  combine_k<<<T_, 256, 0, stream>>>(eoutB, row_of, tww, ylat);

  // out += ylat @ fc2^T
  gemm_nt<1, 3><<<dim3(D_ / BN, T_ / BM, 1), 256, 0, stream>>>(
      ylat, fc2, out, T_, DL_, DL_, DL_, D_, 0, 0, 0, nullptr, nullptr);
}

// Round 2
// 979.323 us; speedup vs baseline: 1.1738x; 1.1738x over previous
//
#include <hip/hip_runtime.h>

typedef unsigned int u32;
typedef unsigned short u16;
typedef __attribute__((ext_vector_type(4))) float floatx4;
typedef __attribute__((ext_vector_type(8))) __bf16 bf16x8;

#define T_ 2048
#define D_ 2048
#define DL_ 1024
#define E_ 64
#define I_ 768
#define SI_ 4096
#define TOPK 6
#define NGRP 8
#define TOPG 4
#define CAP_ 384

#define BM 128
#define BN 128
#define BK 32

__device__ __forceinline__ u16 f2bf(float f) {
  u32 u = __builtin_bit_cast(u32, f);
  u += 0x7fffu + ((u >> 16) & 1u);  // RNE to bf16 (finite data)
  return (u16)(u >> 16);
}
__device__ __forceinline__ float bf2f(u16 h) {
  return __builtin_bit_cast(float, ((u32)h) << 16);
}

__device__ __forceinline__ void async16(const u16* g, u16* l) {
  __builtin_amdgcn_global_load_lds((const __attribute__((address_space(1))) void*)g,
                                   (__attribute__((address_space(3))) void*)l, 16, 0, 0);
}

// ---------------- fp32 -> bf16 streaming convert (8 elems/thread) ----------------
__global__ __launch_bounds__(256) void cvt_f2b_k(const float* __restrict__ src,
                                                 u16* __restrict__ dst, int n8) {
  int i = blockIdx.x * 256 + threadIdx.x;
  if (i >= n8) return;
  const float4* s4 = (const float4*)src;
  float4 a = s4[2 * i], b = s4[2 * i + 1];
  u32 p0 = (u32)f2bf(a.x) | ((u32)f2bf(a.y) << 16);
  u32 p1 = (u32)f2bf(a.z) | ((u32)f2bf(a.w) << 16);
  u32 p2 = (u32)f2bf(b.x) | ((u32)f2bf(b.y) << 16);
  u32 p3 = (u32)f2bf(b.z) | ((u32)f2bf(b.w) << 16);
  ((uint4*)dst)[i] = make_uint4(p0, p1, p2, p3);
}

// ---------------- gate logits: [T,E] = x @ gate_w^T in fp32 ----------------
__global__ __launch_bounds__(256) void gate_logits_k(const float* __restrict__ x,
                                                     const float* __restrict__ gw,
                                                     float* __restrict__ logits) {
  __shared__ float xs[16 * 65];
  __shared__ float wsd[64 * 65];
  const int tid = threadIdx.x;
  const int t0 = blockIdx.x * 16;
  const int tl = tid & 15, eb = (tid >> 4) * 4;
  const int xr = tid >> 4, xc = (tid & 15) * 4;
  const int wr = tid >> 2, wc = (tid & 3) * 16;
  float acc[4] = {0.f, 0.f, 0.f, 0.f};
  for (int kc = 0; kc < D_; kc += 64) {
    __syncthreads();
    float4 xv = *(const float4*)&x[(size_t)(t0 + xr) * D_ + kc + xc];
    xs[xr * 65 + xc + 0] = xv.x;
    xs[xr * 65 + xc + 1] = xv.y;
    xs[xr * 65 + xc + 2] = xv.z;
    xs[xr * 65 + xc + 3] = xv.w;
#pragma unroll
    for (int i = 0; i < 4; ++i) {
      float4 wv = *(const float4*)&gw[(size_t)wr * D_ + kc + wc + i * 4];
      wsd[wr * 65 + wc + i * 4 + 0] = wv.x;
      wsd[wr * 65 + wc + i * 4 + 1] = wv.y;
      wsd[wr * 65 + wc + i * 4 + 2] = wv.z;
      wsd[wr * 65 + wc + i * 4 + 3] = wv.w;
    }
    __syncthreads();
#pragma unroll 4
    for (int kk = 0; kk < 64; ++kk) {
      float xvv = xs[tl * 65 + kk];
#pragma unroll
      for (int q = 0; q < 4; ++q) acc[q] += xvv * wsd[(eb + q) * 65 + kk];
    }
  }
#pragma unroll
  for (int q = 0; q < 4; ++q) logits[(size_t)(t0 + tl) * E_ + eb + q] = acc[q];
}

// ---------------- routing ----------------
__global__ __launch_bounds__(256) void route_k(const float* __restrict__ logits,
                                               const float* __restrict__ bias,
                                               int* __restrict__ cnts,
                                               int* __restrict__ etok,
                                               int* __restrict__ row_of,
                                               float* __restrict__ tww) {
  int t = blockIdx.x * 256 + threadIdx.x;
  if (t >= T_) return;
  float s[E_], cand[E_];
  float gs[NGRP];
  for (int e = 0; e < E_; ++e) {
    float lg = logits[(size_t)t * E_ + e];
    float sv = 1.f / (1.f + __expf(-lg));
    s[e] = sv;
    cand[e] = sv + bias[e];
  }
  for (int g = 0; g < NGRP; ++g) {
    float m1 = -1e30f, m2 = -1e30f;
    for (int j = 0; j < 8; ++j) {
      float v = cand[g * 8 + j];
      if (v > m1) { m2 = m1; m1 = v; }
      else if (v > m2) m2 = v;
    }
    gs[g] = m1 + m2;
  }
  bool gsel[NGRP];
  for (int g = 0; g < NGRP; ++g) gsel[g] = false;
  for (int r = 0; r < TOPG; ++r) {
    float best = -1e30f; int bi = 0;
    for (int g = 0; g < NGRP; ++g)
      if (!gsel[g] && gs[g] > best) { best = gs[g]; bi = g; }
    gsel[bi] = true;
  }
  for (int e = 0; e < E_; ++e)
    if (!gsel[e >> 3]) cand[e] = 0.0f;
  float wsum = 0.f; int eid[TOPK]; float wv[TOPK];
  for (int r = 0; r < TOPK; ++r) {
    float best = -1e30f; int bi = 0;
    for (int e = 0; e < E_; ++e)
      if (cand[e] > best) { best = cand[e]; bi = e; }
    cand[bi] = -1e30f;
    eid[r] = bi; wv[r] = s[bi]; wsum += s[bi];
  }
  float inv = 2.5f / (wsum + 1e-20f);
  for (int r = 0; r < TOPK; ++r) {
    int e = eid[r];
    int slot = atomicAdd(&cnts[e], 1);
    int rowid = -1;
    if (slot < CAP_) { rowid = e * CAP_ + slot; etok[rowid] = t; }
    row_of[t * TOPK + r] = rowid;
    tww[t * TOPK + r] = wv[r] * inv;
  }
}

// ---------------- m97-style all-bf16 NT GEMM: C[M,N] = A[M,K] * B[N,K]^T ----------------
// EPI: 0 = store bf16, 1 = relu^2 store bf16, 2 = store fp32, 3 = accumulate fp32
template <int EPI, bool GATHER>
__global__ __launch_bounds__(256) void gemm_bf(const u16* __restrict__ A,
                                               const u16* __restrict__ B,
                                               void* __restrict__ Cp,
                                               int M, int K, int ldA, int ldB, int ldC,
                                               long sAe, long sBe, long sCe,
                                               const int* __restrict__ counts,
                                               const int* __restrict__ gather) {
  __shared__ u16 As[BM * BK];
  __shared__ u16 Bs[BN * BK];
  const int e = blockIdx.z;
  int Mloc = M;
  if (counts) { Mloc = counts[e]; if (Mloc > CAP_) Mloc = CAP_; }
  const int m0 = blockIdx.y * BM;
  if (m0 >= Mloc) return;
  const int n0 = blockIdx.x * BN;
  const int tid = threadIdx.x;
  const int wave = tid >> 6, lane = tid & 63;
  const int lrow = lane >> 2;        // 0..15
  const int lcol = (lane & 3) * 8;   // 0,8,16,24

  // per-lane global source rows (fixed across K loop)
  int ar0 = m0 + wave * 32 + lrow;
  int ar1 = ar0 + 16;
  const u16 *aS0, *aS1;
  if (GATHER) {
    int t0i = (ar0 < Mloc) ? gather[e * CAP_ + ar0] : 0;
    int t1i = (ar1 < Mloc) ? gather[e * CAP_ + ar1] : 0;
    aS0 = A + (size_t)t0i * ldA + lcol;
    aS1 = A + (size_t)t1i * ldA + lcol;
  } else {
    aS0 = A + (size_t)e * sAe + (size_t)ar0 * ldA + lcol;
    aS1 = A + (size_t)e * sAe + (size_t)ar1 * ldA + lcol;
  }
  int br0 = n0 + wave * 32 + lrow, br1 = br0 + 16;
  const u16* bS0 = B + (size_t)e * sBe + (size_t)br0 * ldB + lcol;
  const u16* bS1 = B + (size_t)e * sBe + (size_t)br1 * ldB + lcol;

  // wave-uniform LDS destinations (lane-linear fill: base + lane*16B)
  u16* lA0 = &As[(wave * 32 + 0) * BK];
  u16* lA1 = &As[(wave * 32 + 16) * BK];
  u16* lB0 = &Bs[(wave * 32 + 0) * BK];
  u16* lB1 = &Bs[(wave * 32 + 16) * BK];

  floatx4 acc[4][4];
#pragma unroll
  for (int i = 0; i < 4; ++i)
#pragma unroll
    for (int j = 0; j < 4; ++j) acc[i][j] = floatx4{0.f, 0.f, 0.f, 0.f};

  const int wm = (wave & 1) * 64, wn = (wave >> 1) * 64;
  const int lr = lane & 15, lk = (lane >> 4) * 8;

  for (int kt = 0; kt < K; kt += BK) {
    __syncthreads();
    async16(aS0 + kt, lA0);
    async16(aS1 + kt, lA1);
    async16(bS0 + kt, lB0);
    async16(bS1 + kt, lB1);
    __syncthreads();
    bf16x8 af[4], bfr[4];
#pragma unroll
    for (int i = 0; i < 4; ++i)
      af[i] = *(const bf16x8*)&As[(wm + i * 16 + lr) * BK + lk];
#pragma unroll
    for (int j = 0; j < 4; ++j)
      bfr[j] = *(const bf16x8*)&Bs[(wn + j * 16 + lr) * BK + lk];
#pragma unroll
    for (int i = 0; i < 4; ++i)
#pragma unroll
      for (int j = 0; j < 4; ++j)
        acc[i][j] = __builtin_amdgcn_mfma_f32_16x16x32_bf16(af[i], bfr[j], acc[i][j], 0, 0, 0);
  }

  const int rbase = (lane >> 4) * 4;
#pragma unroll
  for (int i = 0; i < 4; ++i) {
#pragma unroll
    for (int r = 0; r < 4; ++r) {
      int grow = m0 + wm + i * 16 + rbase + r;
      if (grow >= Mloc) continue;
      size_t crow = (size_t)sCe * e + (size_t)grow * ldC;
#pragma unroll
      for (int j = 0; j < 4; ++j) {
        int gcol = n0 + wn + j * 16 + lr;
        float v = acc[i][j][r];
        if constexpr (EPI == 0) {
          ((u16*)Cp)[crow + gcol] = f2bf(v);
        } else if constexpr (EPI == 1) {
          v = fmaxf(v, 0.f); v *= v;
          ((u16*)Cp)[crow + gcol] = f2bf(v);
        } else if constexpr (EPI == 2) {
          ((float*)Cp)[crow + gcol] = v;
        } else {
          ((float*)Cp)[crow + gcol] += v;
        }
      }
    }
  }
}

// ---------------- fallback fp32-B GEMM (round-1 path) ----------------
#define LDS_PAD 40
template <int ATYPE, int EPI>
__global__ __launch_bounds__(256, 2) void gemm_nt(const void* __restrict__ Ap,
                                                  const float* __restrict__ Bp,
                                                  void* __restrict__ Cp,
                                                  int M, int K, int ldA, int ldB, int ldC,
                                                  long sAe, long sBe, long sCe,
                                                  const int* __restrict__ counts,
                                                  const int* __restrict__ gather) {
  __shared__ u16 As[BM * LDS_PAD];
  __shared__ u16 Bs[BN * LDS_PAD];
  const int e = blockIdx.z;
  int Mloc = M;
  if (counts) { Mloc = counts[e]; if (Mloc > CAP_) Mloc = CAP_; }
  const int m0 = blockIdx.y * BM;
  if (m0 >= Mloc) return;
  const int n0 = blockIdx.x * BN;
  const int tid = threadIdx.x;
  const int row = tid >> 1;
  const int colb = (tid & 1) * 16;
  const int arow = m0 + row;
  int arowIdx;
  if (gather) arowIdx = (arow < Mloc) ? gather[e * CAP_ + arow] : 0;
  else arowIdx = arow;
  const float* Af32 = (const float*)Ap + (size_t)e * sAe + (size_t)arowIdx * ldA;
  const u16* Abf = (const u16*)Ap + (size_t)e * sAe + (size_t)arowIdx * ldA;
  const float* Brow = Bp + (size_t)e * sBe + (size_t)(n0 + row) * ldB;
  float4 ra[4]; uint4 rab[2]; float4 rb[4];
  auto loadAB = [&](int kt) {
    if constexpr (ATYPE == 0) {
#pragma unroll
      for (int i = 0; i < 4; ++i) ra[i] = *(const float4*)&Af32[kt + colb + i * 4];
    } else {
#pragma unroll
      for (int i = 0; i < 2; ++i) rab[i] = *(const uint4*)&Abf[kt + colb + i * 8];
    }
#pragma unroll
    for (int i = 0; i < 4; ++i) rb[i] = *(const float4*)&Brow[kt + colb + i * 4];
  };
  auto stage = [&]() {
    uint4* ad = (uint4*)&As[row * LDS_PAD + colb];
    if constexpr (ATYPE == 0) {
      u32 w[8];
#pragma unroll
      for (int i = 0; i < 4; ++i) {
        w[2 * i] = (u32)f2bf(ra[i].x) | ((u32)f2bf(ra[i].y) << 16);
        w[2 * i + 1] = (u32)f2bf(ra[i].z) | ((u32)f2bf(ra[i].w) << 16);
      }
      ad[0] = make_uint4(w[0], w[1], w[2], w[3]);
      ad[1] = make_uint4(w[4], w[5], w[6], w[7]);
    } else {
      ad[0] = rab[0]; ad[1] = rab[1];
    }
    u32 wb[8];
#pragma unroll
    for (int i = 0; i < 4; ++i) {
      wb[2 * i] = (u32)f2bf(rb[i].x) | ((u32)f2bf(rb[i].y) << 16);
      wb[2 * i + 1] = (u32)f2bf(rb[i].z) | ((u32)f2bf(rb[i].w) << 16);
    }
    uint4* bd = (uint4*)&Bs[row * LDS_PAD + colb];
    bd[0] = make_uint4(wb[0], wb[1], wb[2], wb[3]);
    bd[1] = make_uint4(wb[4], wb[5], wb[6], wb[7]);
  };
  floatx4 acc[4][4];
#pragma unroll
  for (int i = 0; i < 4; ++i)
#pragma unroll
    for (int j = 0; j < 4; ++j) acc[i][j] = floatx4{0.f, 0.f, 0.f, 0.f};
  const int wave = tid >> 6, lane = tid & 63;
  const int wm = (wave & 1) * 64, wn = (wave >> 1) * 64;
  const int lr = lane & 15, lk = (lane >> 4) * 8;
  loadAB(0);
  for (int kt = 0; kt < K; kt += BK) {
    __syncthreads();
    stage();
    __syncthreads();
    if (kt + BK < K) loadAB(kt + BK);
    bf16x8 af[4], bfr[4];
#pragma unroll
    for (int i = 0; i < 4; ++i)
      af[i] = *(const bf16x8*)&As[(wm + i * 16 + lr) * LDS_PAD + lk];
#pragma unroll
    for (int j = 0; j < 4; ++j)
      bfr[j] = *(const bf16x8*)&Bs[(wn + j * 16 + lr) * LDS_PAD + lk];
#pragma unroll
    for (int i = 0; i < 4; ++i)
#pragma unroll
      for (int j = 0; j < 4; ++j)
        acc[i][j] = __builtin_amdgcn_mfma_f32_16x16x32_bf16(af[i], bfr[j], acc[i][j], 0, 0, 0);
  }
  const int rbase = (lane >> 4) * 4;
#pragma unroll
  for (int i = 0; i < 4; ++i) {
#pragma unroll
    for (int r = 0; r < 4; ++r) {
      int grow = m0 + wm + i * 16 + rbase + r;
      if (grow >= Mloc) continue;
      size_t crow = (size_t)sCe * e + (size_t)grow * ldC;
#pragma unroll
      for (int j = 0; j < 4; ++j) {
        int gcol = n0 + wn + j * 16 + lr;
        float v = acc[i][j][r];
        if constexpr (EPI == 0) {
          ((u16*)Cp)[crow + gcol] = f2bf(v);
        } else if constexpr (EPI == 1) {
          v = fmaxf(v, 0.f); v *= v;
          ((u16*)Cp)[crow + gcol] = f2bf(v);
        } else if constexpr (EPI == 2) {
          ((float*)Cp)[crow + gcol] = v;
        } else {
          ((float*)Cp)[crow + gcol] += v;
        }
      }
    }
  }
}

// ---------------- combine ----------------
__global__ __launch_bounds__(256) void combine_k(const u16* __restrict__ eout,
                                                 const int* __restrict__ row_of,
                                                 const float* __restrict__ tww,
                                                 u16* __restrict__ ylat) {
  int t = blockIdx.x;
  int c0 = threadIdx.x * 4;
  float a0 = 0.f, a1 = 0.f, a2 = 0.f, a3 = 0.f;
#pragma unroll
  for (int k = 0; k < TOPK; ++k) {
    int r = row_of[t * TOPK + k];
    float w = tww[t * TOPK + k];
    if (r >= 0) {
      uint2 v = *(const uint2*)&eout[(size_t)r * DL_ + c0];
      a0 += w * bf2f((u16)(v.x & 0xffffu));
      a1 += w * bf2f((u16)(v.x >> 16));
      a2 += w * bf2f((u16)(v.y & 0xffffu));
      a3 += w * bf2f((u16)(v.y >> 16));
    }
  }
  u32 o0 = (u32)f2bf(a0) | ((u32)f2bf(a1) << 16);
  u32 o1 = (u32)f2bf(a2) | ((u32)f2bf(a3) << 16);
  *(uint2*)&ylat[(size_t)t * DL_ + c0] = make_uint2(o0, o1);
}

extern "C" void kernel_launch(void* const* d_in, const int* in_sizes, int n_in,
                              void* d_out, int out_size, void* d_ws, size_t ws_size,
                              hipStream_t stream) {
  (void)in_sizes; (void)n_in; (void)out_size;
  const float* x = (const float*)d_in[0];
  const float* gw = (const float*)d_in[1];
  const float* gbias = (const float*)d_in[2];
  const float* fc1 = (const float*)d_in[3];
  const float* fc2 = (const float*)d_in[4];
  const float* w1 = (const float*)d_in[5];
  const float* w2 = (const float*)d_in[6];
  const float* sw1 = (const float*)d_in[7];
  const float* sw2 = (const float*)d_in[8];
  float* out = (float*)d_out;

  char* ws = (char*)d_ws;
  size_t off = 0;
  auto alloc = [&](size_t bytes) {
    char* p = ws + off;
    off += (bytes + 255) & ~(size_t)255;
    return p;
  };
  float* logits = (float*)alloc((size_t)T_ * E_ * 4);
  int* cnts = (int*)alloc(E_ * 4);
  int* etok = (int*)alloc((size_t)E_ * CAP_ * 4);
  int* row_of = (int*)alloc((size_t)T_ * TOPK * 4);
  float* tww = (float*)alloc((size_t)T_ * TOPK * 4);
  u16* xl = (u16*)alloc((size_t)T_ * DL_ * 2);
  u16* ylat = (u16*)alloc((size_t)T_ * DL_ * 2);

  // fast-path extra buffers
  size_t big1_elems = (size_t)E_ * CAP_ * I_;  // >= T_*SI_
  if ((size_t)T_ * SI_ > big1_elems) big1_elems = (size_t)T_ * SI_;
  size_t need_fast = off + (((size_t)T_ * D_ * 2 + 255) & ~255ul)         // xbf
                     + (((size_t)D_ * DL_ * 2 + 255) & ~255ul)            // fc2b
                     + ((big1_elems * 2 + 255) & ~255ul)                  // hs/h
                     + (((size_t)E_ * CAP_ * DL_ * 2 + 255) & ~255ul)     // eout
                     + (((size_t)E_ * I_ * DL_ * 2 + 255) & ~255ul);      // wbuf

  hipMemsetAsync(cnts, 0, E_ * 4, stream);
  gate_logits_k<<<T_ / 16, 256, 0, stream>>>(x, gw, logits);
  route_k<<<T_ / 256, 256, 0, stream>>>(logits, gbias, cnts, etok, row_of, tww);

  if (ws_size >= need_fast) {
    u16* xbf = (u16*)alloc((size_t)T_ * D_ * 2);
    u16* fc2b = (u16*)alloc((size_t)D_ * DL_ * 2);
    u16* big1 = (u16*)alloc(big1_elems * 2);              // hs then h
    u16* eoutB = (u16*)alloc((size_t)E_ * CAP_ * DL_ * 2);
    u16* wbuf = (u16*)alloc((size_t)E_ * I_ * DL_ * 2);   // sw1|sw2|fc1, then w1, then w2
    u16* sw1b = wbuf;
    u16* sw2b = wbuf + (size_t)SI_ * D_;
    u16* fc1b = wbuf + 2 * (size_t)SI_ * D_;

    // converts (weights reused later are placed before their consumers)
    cvt_f2b_k<<<(T_ * D_ / 8 + 255) / 256, 256, 0, stream>>>(x, xbf, T_ * D_ / 8);
    cvt_f2b_k<<<(SI_ * D_ / 8 + 255) / 256, 256, 0, stream>>>(sw1, sw1b, SI_ * D_ / 8);
    cvt_f2b_k<<<(SI_ * D_ / 8 + 255) / 256, 256, 0, stream>>>(sw2, sw2b, SI_ * D_ / 8);
    cvt_f2b_k<<<(DL_ * D_ / 8 + 255) / 256, 256, 0, stream>>>(fc1, fc1b, DL_ * D_ / 8);
    cvt_f2b_k<<<(D_ * DL_ / 8 + 255) / 256, 256, 0, stream>>>(fc2, fc2b, D_ * DL_ / 8);

    // shared path: hs = relu2(x @ sw1^T); out = hs @ sw2^T
    gemm_bf<1, false><<<dim3(SI_ / BN, T_ / BM, 1), 256, 0, stream>>>(
        xbf, sw1b, big1, T_, D_, D_, D_, SI_, 0, 0, 0, nullptr, nullptr);
    gemm_bf<2, false><<<dim3(D_ / BN, T_ / BM, 1), 256, 0, stream>>>(
        big1, sw2b, out, T_, SI_, SI_, SI_, D_, 0, 0, 0, nullptr, nullptr);

    // latent projection: xl = x @ fc1^T
    gemm_bf<0, false><<<dim3(DL_ / BN, T_ / BM, 1), 256, 0, stream>>>(
        xbf, fc1b, xl, T_, D_, D_, D_, DL_, 0, 0, 0, nullptr, nullptr);

    // expert FFN stage 1 (w1 convert overwrites sw*/fc1 region — all dead by now)
    int nw = E_ * I_ * DL_ / 8;
    cvt_f2b_k<<<(nw + 255) / 256, 256, 0, stream>>>(w1, wbuf, nw);
    gemm_bf<1, true><<<dim3(I_ / BN, CAP_ / BM, E_), 256, 0, stream>>>(
        xl, wbuf, big1, CAP_, DL_, DL_, DL_, I_,
        0, (long)I_ * DL_, (long)CAP_ * I_, cnts, etok);

    // expert FFN stage 2
    cvt_f2b_k<<<(nw + 255) / 256, 256, 0, stream>>>(w2, wbuf, nw);
    gemm_bf<0, false><<<dim3(DL_ / BN, CAP_ / BM, E_), 256, 0, stream>>>(
        big1, wbuf, eoutB, CAP_, I_, I_, I_, DL_,
        (long)CAP_ * I_, (long)DL_ * I_, (long)CAP_ * DL_, cnts, nullptr);

    combine_k<<<T_, 256, 0, stream>>>(eoutB, row_of, tww, ylat);

    // out += ylat @ fc2^T
    gemm_bf<3, false><<<dim3(D_ / BN, T_ / BM, 1), 256, 0, stream>>>(
        ylat, fc2b, out, T_, DL_, DL_, DL_, D_, 0, 0, 0, nullptr, nullptr);
  } else {
    // fallback: round-1 fp32-staging path
    char* big = alloc((size_t)E_ * CAP_ * I_ * 2 + (size_t)E_ * CAP_ * DL_ * 2);
    u16* hs = (u16*)big;
    u16* h = (u16*)big;
    u16* eoutB = (u16*)(big + (size_t)E_ * CAP_ * I_ * 2);

    gemm_nt<0, 1><<<dim3(SI_ / BN, T_ / BM, 1), 256, 0, stream>>>(
        x, sw1, hs, T_, D_, D_, D_, SI_, 0, 0, 0, nullptr, nullptr);
    gemm_nt<1, 2><<<dim3(D_ / BN, T_ / BM, 1), 256, 0, stream>>>(
        hs, sw2, out, T_, SI_, SI_, SI_, D_, 0, 0, 0, nullptr, nullptr);
    gemm_nt<0, 0><<<dim3(DL_ / BN, T_ / BM, 1), 256, 0, stream>>>(
        x, fc1, xl, T_, D_, D_, D_, DL_, 0, 0, 0, nullptr, nullptr);
    gemm_nt<1, 1><<<dim3(I_ / BN, CAP_ / BM, E_), 256, 0, stream>>>(
        xl, w1, h, CAP_, DL_, DL_, DL_, I_,
        0, (long)I_ * DL_, (long)CAP_ * I_, cnts, etok);
    gemm_nt<1, 0><<<dim3(DL_ / BN, CAP_ / BM, E_), 256, 0, stream>>>(
        h, w2, eoutB, CAP_, I_, I_, I_, DL_,
        (long)CAP_ * I_, (long)DL_ * I_, (long)CAP_ * DL_, cnts, nullptr);
    combine_k<<<T_, 256, 0, stream>>>(eoutB, row_of, tww, ylat);
    gemm_nt<1, 3><<<dim3(D_ / BN, T_ / BM, 1), 256, 0, stream>>>(
        ylat, fc2, out, T_, DL_, DL_, DL_, D_, 0, 0, 0, nullptr, nullptr);
  }
}

// Round 3
// 884.076 us; speedup vs baseline: 1.3002x; 1.1077x over previous
//
#include <hip/hip_runtime.h>

typedef unsigned int u32;
typedef unsigned short u16;
typedef __attribute__((ext_vector_type(4))) float floatx4;
typedef __attribute__((ext_vector_type(8))) __bf16 bf16x8;

#define T_ 2048
#define D_ 2048
#define DL_ 1024
#define E_ 64
#define I_ 768
#define SI_ 4096
#define TOPK 6
#define NGRP 8
#define TOPG 4
#define CAP_ 384

#define BM 128
#define BK 32

__device__ __forceinline__ u16 f2bf(float f) {
  u32 u = __builtin_bit_cast(u32, f);
  u += 0x7fffu + ((u >> 16) & 1u);  // RNE to bf16 (finite data)
  return (u16)(u >> 16);
}
__device__ __forceinline__ float bf2f(u16 h) {
  return __builtin_bit_cast(float, ((u32)h) << 16);
}

__device__ __forceinline__ void async16(const u16* g, u16* l) {
  __builtin_amdgcn_global_load_lds((const __attribute__((address_space(1))) void*)g,
                                   (__attribute__((address_space(3))) void*)l, 16, 0, 0);
}

// ---------------- fp32 -> bf16 streaming convert (8 elems/thread) ----------------
__global__ __launch_bounds__(256) void cvt_f2b_k(const float* __restrict__ src,
                                                 u16* __restrict__ dst, int n8) {
  int i = blockIdx.x * 256 + threadIdx.x;
  if (i >= n8) return;
  const float4* s4 = (const float4*)src;
  float4 a = s4[2 * i], b = s4[2 * i + 1];
  u32 p0 = (u32)f2bf(a.x) | ((u32)f2bf(a.y) << 16);
  u32 p1 = (u32)f2bf(a.z) | ((u32)f2bf(a.w) << 16);
  u32 p2 = (u32)f2bf(b.x) | ((u32)f2bf(b.y) << 16);
  u32 p3 = (u32)f2bf(b.z) | ((u32)f2bf(b.w) << 16);
  ((uint4*)dst)[i] = make_uint4(p0, p1, p2, p3);
}

// ---------------- gate logits: [T,E] = x @ gate_w^T in fp32, 2 blocks per 16-token group ----------------
__global__ __launch_bounds__(256) void gate_logits_k(const float* __restrict__ x,
                                                     const float* __restrict__ gw,
                                                     float* __restrict__ logits) {
  __shared__ float xs[16 * 65];
  __shared__ float wsd[32 * 65];
  const int tid = threadIdx.x;
  const int t0 = blockIdx.x * 16;
  const int e0 = blockIdx.y * 32;
  const int tl = tid & 15, eb = (tid >> 4) * 2;
  const int xr = tid >> 4, xc = (tid & 15) * 4;
  const int wr = tid >> 3, wc = (tid & 7) * 8;
  float acc[2] = {0.f, 0.f};
  for (int kc = 0; kc < D_; kc += 64) {
    __syncthreads();
    float4 xv = *(const float4*)&x[(size_t)(t0 + xr) * D_ + kc + xc];
    xs[xr * 65 + xc + 0] = xv.x;
    xs[xr * 65 + xc + 1] = xv.y;
    xs[xr * 65 + xc + 2] = xv.z;
    xs[xr * 65 + xc + 3] = xv.w;
#pragma unroll
    for (int i = 0; i < 2; ++i) {
      float4 wv = *(const float4*)&gw[(size_t)(e0 + wr) * D_ + kc + wc + i * 4];
      wsd[wr * 65 + wc + i * 4 + 0] = wv.x;
      wsd[wr * 65 + wc + i * 4 + 1] = wv.y;
      wsd[wr * 65 + wc + i * 4 + 2] = wv.z;
      wsd[wr * 65 + wc + i * 4 + 3] = wv.w;
    }
    __syncthreads();
#pragma unroll 4
    for (int kk = 0; kk < 64; ++kk) {
      float xvv = xs[tl * 65 + kk];
      acc[0] += xvv * wsd[eb * 65 + kk];
      acc[1] += xvv * wsd[(eb + 1) * 65 + kk];
    }
  }
  logits[(size_t)(t0 + tl) * E_ + e0 + eb + 0] = acc[0];
  logits[(size_t)(t0 + tl) * E_ + e0 + eb + 1] = acc[1];
}

// ---------------- routing: one token per wave, lane = expert ----------------
__global__ __launch_bounds__(256) void route_k(const float* __restrict__ logits,
                                               const float* __restrict__ bias,
                                               int* __restrict__ cnts,
                                               int* __restrict__ etok,
                                               int* __restrict__ row_of,
                                               float* __restrict__ tww) {
  const int wid = threadIdx.x >> 6, lane = threadIdx.x & 63;
  const int t = blockIdx.x * 4 + wid;
  float lg = logits[(size_t)t * E_ + lane];
  float s = 1.f / (1.f + __expf(-lg));
  float sb = s + bias[lane];
  const int g = lane >> 3;
  // group top-2 sum (8-lane clusters; xor 1/2/4 stays in-cluster)
  float m1 = sb;
  m1 = fmaxf(m1, __shfl_xor(m1, 1));
  m1 = fmaxf(m1, __shfl_xor(m1, 2));
  m1 = fmaxf(m1, __shfl_xor(m1, 4));
  unsigned long long b1 = __ballot(sb == m1);
  int am = __ffsll((unsigned long long)((b1 >> (g * 8)) & 0xFFull)) - 1 + g * 8;
  float v2 = (lane == am) ? -1e30f : sb;
  float m2 = v2;
  m2 = fmaxf(m2, __shfl_xor(m2, 1));
  m2 = fmaxf(m2, __shfl_xor(m2, 2));
  m2 = fmaxf(m2, __shfl_xor(m2, 4));
  float gs = m1 + m2;
  // top-4 groups (each lane redundantly)
  float gsv[NGRP];
#pragma unroll
  for (int gg = 0; gg < NGRP; ++gg) gsv[gg] = __shfl(gs, gg * 8);
  unsigned selm = 0;
#pragma unroll
  for (int r = 0; r < TOPG; ++r) {
    float best = -1e30f; int bi = 0;
#pragma unroll
    for (int gg = 0; gg < NGRP; ++gg)
      if (!((selm >> gg) & 1) && gsv[gg] > best) { best = gsv[gg]; bi = gg; }
    selm |= 1u << bi;
  }
  float val = ((selm >> g) & 1) ? sb : 0.0f;  // matches reference masked-to-0.0
  // top-6 experts across wave
  float wsum = 0.f; int selr = -1;
#pragma unroll
  for (int r = 0; r < TOPK; ++r) {
    float m = val;
    m = fmaxf(m, __shfl_xor(m, 1));
    m = fmaxf(m, __shfl_xor(m, 2));
    m = fmaxf(m, __shfl_xor(m, 4));
    m = fmaxf(m, __shfl_xor(m, 8));
    m = fmaxf(m, __shfl_xor(m, 16));
    m = fmaxf(m, __shfl_xor(m, 32));
    unsigned long long b2 = __ballot(val == m);
    int am2 = __ffsll(b2) - 1;  // lowest lane = stable tie-break (matches jax)
    if (lane == am2) { selr = r; val = -1e30f; }
    wsum += __shfl(s, am2);
  }
  float inv = 2.5f / (wsum + 1e-20f);
  if (selr >= 0) {
    int slot = atomicAdd(&cnts[lane], 1);
    int rowid = -1;
    if (slot < CAP_) { rowid = lane * CAP_ + slot; etok[rowid] = t; }
    row_of[t * TOPK + selr] = rowid;
    tww[t * TOPK + selr] = s * inv;
  }
}

// ---------------- dbuf all-bf16 NT GEMM: C[M,N] = A[M,K] * B[N,K]^T ----------------
// EPI: 0 = store bf16, 1 = relu^2 store bf16, 2 = store fp32, 3 = accumulate fp32
// BNT: 128 (4 asyncs/lane) or 64 (3 asyncs/lane)
template <int EPI, bool GATHER, int BNT>
__global__ __launch_bounds__(256) void gemm_bf(const u16* __restrict__ A,
                                               const u16* __restrict__ B,
                                               void* __restrict__ Cp,
                                               int M, int K, int ldA, int ldB, int ldC,
                                               long sAe, long sBe, long sCe,
                                               const int* __restrict__ counts,
                                               const int* __restrict__ gather) {
  constexpr int NJ = BNT / 32;  // accumulator tiles in N per wave
  __shared__ u16 As[2][BM * BK];
  __shared__ u16 Bs[2][BNT * BK];
  const int e = blockIdx.z;
  int Mloc = M;
  if (counts) { Mloc = counts[e]; if (Mloc > CAP_) Mloc = CAP_; }
  const int m0 = blockIdx.y * BM;
  if (m0 >= Mloc) return;
  const int n0 = blockIdx.x * BNT;
  const int tid = threadIdx.x;
  const int wave = tid >> 6, lane = tid & 63;
  const int lrow = lane >> 2;        // 0..15
  const int lcol = (lane & 3) * 8;   // 0,8,16,24

  // per-lane global source rows (fixed across K loop)
  int ar0 = m0 + wave * 32 + lrow;
  int ar1 = ar0 + 16;
  const u16 *aS0, *aS1, *bS0, *bS1 = nullptr;
  if (GATHER) {
    int t0i = (ar0 < Mloc) ? gather[e * CAP_ + ar0] : 0;
    int t1i = (ar1 < Mloc) ? gather[e * CAP_ + ar1] : 0;
    aS0 = A + (size_t)t0i * ldA + lcol;
    aS1 = A + (size_t)t1i * ldA + lcol;
  } else {
    aS0 = A + (size_t)e * sAe + (size_t)ar0 * ldA + lcol;
    aS1 = A + (size_t)e * sAe + (size_t)ar1 * ldA + lcol;
  }
  if (BNT == 128) {
    int br0 = n0 + wave * 32 + lrow;
    bS0 = B + (size_t)e * sBe + (size_t)br0 * ldB + lcol;
    bS1 = B + (size_t)e * sBe + (size_t)(br0 + 16) * ldB + lcol;
  } else {
    int br0 = n0 + wave * 16 + lrow;
    bS0 = B + (size_t)e * sBe + (size_t)br0 * ldB + lcol;
  }

  auto issue = [&](int kt, int p) {
    async16(aS0 + kt, &As[p][(wave * 32 + 0) * BK]);
    async16(aS1 + kt, &As[p][(wave * 32 + 16) * BK]);
    if (BNT == 128) {
      async16(bS0 + kt, &Bs[p][(wave * 32 + 0) * BK]);
      async16(bS1 + kt, &Bs[p][(wave * 32 + 16) * BK]);
    } else {
      async16(bS0 + kt, &Bs[p][(wave * 16) * BK]);
    }
  };

  floatx4 acc[4][NJ];
#pragma unroll
  for (int i = 0; i < 4; ++i)
#pragma unroll
    for (int j = 0; j < NJ; ++j) acc[i][j] = floatx4{0.f, 0.f, 0.f, 0.f};

  const int wm = (wave & 1) * 64;
  const int wn = (wave >> 1) * (BNT == 128 ? 64 : 32);
  const int lr = lane & 15, lk = (lane >> 4) * 8;

  issue(0, 0);
  int p = 0;
  for (int kt = 0; kt < K; kt += BK, p ^= 1) {
    __syncthreads();                        // drains asyncs for buf p; prev reads of p^1 done
    if (kt + BK < K) issue(kt + BK, p ^ 1); // in flight during this tile's compute
    bf16x8 af[4], bfr[NJ];
#pragma unroll
    for (int i = 0; i < 4; ++i)
      af[i] = *(const bf16x8*)&As[p][(wm + i * 16 + lr) * BK + lk];
#pragma unroll
    for (int j = 0; j < NJ; ++j)
      bfr[j] = *(const bf16x8*)&Bs[p][(wn + j * 16 + lr) * BK + lk];
#pragma unroll
    for (int i = 0; i < 4; ++i)
#pragma unroll
      for (int j = 0; j < NJ; ++j)
        acc[i][j] = __builtin_amdgcn_mfma_f32_16x16x32_bf16(af[i], bfr[j], acc[i][j], 0, 0, 0);
  }

  const int rbase = (lane >> 4) * 4;
#pragma unroll
  for (int i = 0; i < 4; ++i) {
#pragma unroll
    for (int r = 0; r < 4; ++r) {
      int grow = m0 + wm + i * 16 + rbase + r;
      if (grow >= Mloc) continue;
      size_t crow = (size_t)sCe * e + (size_t)grow * ldC;
#pragma unroll
      for (int j = 0; j < NJ; ++j) {
        int gcol = n0 + wn + j * 16 + lr;
        float v = acc[i][j][r];
        if constexpr (EPI == 0) {
          ((u16*)Cp)[crow + gcol] = f2bf(v);
        } else if constexpr (EPI == 1) {
          v = fmaxf(v, 0.f); v *= v;
          ((u16*)Cp)[crow + gcol] = f2bf(v);
        } else if constexpr (EPI == 2) {
          ((float*)Cp)[crow + gcol] = v;
        } else {
          ((float*)Cp)[crow + gcol] += v;
        }
      }
    }
  }
}

// ---------------- fallback fp32-B GEMM (round-1 path) ----------------
#define LDS_PAD 40
#define BNF 128
template <int ATYPE, int EPI>
__global__ __launch_bounds__(256, 2) void gemm_nt(const void* __restrict__ Ap,
                                                  const float* __restrict__ Bp,
                                                  void* __restrict__ Cp,
                                                  int M, int K, int ldA, int ldB, int ldC,
                                                  long sAe, long sBe, long sCe,
                                                  const int* __restrict__ counts,
                                                  const int* __restrict__ gather) {
  __shared__ u16 As[BM * LDS_PAD];
  __shared__ u16 Bs[BNF * LDS_PAD];
  const int e = blockIdx.z;
  int Mloc = M;
  if (counts) { Mloc = counts[e]; if (Mloc > CAP_) Mloc = CAP_; }
  const int m0 = blockIdx.y * BM;
  if (m0 >= Mloc) return;
  const int n0 = blockIdx.x * BNF;
  const int tid = threadIdx.x;
  const int row = tid >> 1;
  const int colb = (tid & 1) * 16;
  const int arow = m0 + row;
  int arowIdx;
  if (gather) arowIdx = (arow < Mloc) ? gather[e * CAP_ + arow] : 0;
  else arowIdx = arow;
  const float* Af32 = (const float*)Ap + (size_t)e * sAe + (size_t)arowIdx * ldA;
  const u16* Abf = (const u16*)Ap + (size_t)e * sAe + (size_t)arowIdx * ldA;
  const float* Brow = Bp + (size_t)e * sBe + (size_t)(n0 + row) * ldB;
  float4 ra[4]; uint4 rab[2]; float4 rb[4];
  auto loadAB = [&](int kt) {
    if constexpr (ATYPE == 0) {
#pragma unroll
      for (int i = 0; i < 4; ++i) ra[i] = *(const float4*)&Af32[kt + colb + i * 4];
    } else {
#pragma unroll
      for (int i = 0; i < 2; ++i) rab[i] = *(const uint4*)&Abf[kt + colb + i * 8];
    }
#pragma unroll
    for (int i = 0; i < 4; ++i) rb[i] = *(const float4*)&Brow[kt + colb + i * 4];
  };
  auto stage = [&]() {
    uint4* ad = (uint4*)&As[row * LDS_PAD + colb];
    if constexpr (ATYPE == 0) {
      u32 w[8];
#pragma unroll
      for (int i = 0; i < 4; ++i) {
        w[2 * i] = (u32)f2bf(ra[i].x) | ((u32)f2bf(ra[i].y) << 16);
        w[2 * i + 1] = (u32)f2bf(ra[i].z) | ((u32)f2bf(ra[i].w) << 16);
      }
      ad[0] = make_uint4(w[0], w[1], w[2], w[3]);
      ad[1] = make_uint4(w[4], w[5], w[6], w[7]);
    } else {
      ad[0] = rab[0]; ad[1] = rab[1];
    }
    u32 wb[8];
#pragma unroll
    for (int i = 0; i < 4; ++i) {
      wb[2 * i] = (u32)f2bf(rb[i].x) | ((u32)f2bf(rb[i].y) << 16);
      wb[2 * i + 1] = (u32)f2bf(rb[i].z) | ((u32)f2bf(rb[i].w) << 16);
    }
    uint4* bd = (uint4*)&Bs[row * LDS_PAD + colb];
    bd[0] = make_uint4(wb[0], wb[1], wb[2], wb[3]);
    bd[1] = make_uint4(wb[4], wb[5], wb[6], wb[7]);
  };
  floatx4 acc[4][4];
#pragma unroll
  for (int i = 0; i < 4; ++i)
#pragma unroll
    for (int j = 0; j < 4; ++j) acc[i][j] = floatx4{0.f, 0.f, 0.f, 0.f};
  const int wave = tid >> 6, lane = tid & 63;
  const int wm = (wave & 1) * 64, wn = (wave >> 1) * 64;
  const int lr = lane & 15, lk = (lane >> 4) * 8;
  loadAB(0);
  for (int kt = 0; kt < K; kt += BK) {
    __syncthreads();
    stage();
    __syncthreads();
    if (kt + BK < K) loadAB(kt + BK);
    bf16x8 af[4], bfr[4];
#pragma unroll
    for (int i = 0; i < 4; ++i)
      af[i] = *(const bf16x8*)&As[(wm + i * 16 + lr) * LDS_PAD + lk];
#pragma unroll
    for (int j = 0; j < 4; ++j)
      bfr[j] = *(const bf16x8*)&Bs[(wn + j * 16 + lr) * LDS_PAD + lk];
#pragma unroll
    for (int i = 0; i < 4; ++i)
#pragma unroll
      for (int j = 0; j < 4; ++j)
        acc[i][j] = __builtin_amdgcn_mfma_f32_16x16x32_bf16(af[i], bfr[j], acc[i][j], 0, 0, 0);
  }
  const int rbase = (lane >> 4) * 4;
#pragma unroll
  for (int i = 0; i < 4; ++i) {
#pragma unroll
    for (int r = 0; r < 4; ++r) {
      int grow = m0 + wm + i * 16 + rbase + r;
      if (grow >= Mloc) continue;
      size_t crow = (size_t)sCe * e + (size_t)grow * ldC;
#pragma unroll
      for (int j = 0; j < 4; ++j) {
        int gcol = n0 + wn + j * 16 + lr;
        float v = acc[i][j][r];
        if constexpr (EPI == 0) {
          ((u16*)Cp)[crow + gcol] = f2bf(v);
        } else if constexpr (EPI == 1) {
          v = fmaxf(v, 0.f); v *= v;
          ((u16*)Cp)[crow + gcol] = f2bf(v);
        } else if constexpr (EPI == 2) {
          ((float*)Cp)[crow + gcol] = v;
        } else {
          ((float*)Cp)[crow + gcol] += v;
        }
      }
    }
  }
}

// ---------------- combine ----------------
__global__ __launch_bounds__(256) void combine_k(const u16* __restrict__ eout,
                                                 const int* __restrict__ row_of,
                                                 const float* __restrict__ tww,
                                                 u16* __restrict__ ylat) {
  int t = blockIdx.x;
  int c0 = threadIdx.x * 4;
  float a0 = 0.f, a1 = 0.f, a2 = 0.f, a3 = 0.f;
#pragma unroll
  for (int k = 0; k < TOPK; ++k) {
    int r = row_of[t * TOPK + k];
    float w = tww[t * TOPK + k];
    if (r >= 0) {
      uint2 v = *(const uint2*)&eout[(size_t)r * DL_ + c0];
      a0 += w * bf2f((u16)(v.x & 0xffffu));
      a1 += w * bf2f((u16)(v.x >> 16));
      a2 += w * bf2f((u16)(v.y & 0xffffu));
      a3 += w * bf2f((u16)(v.y >> 16));
    }
  }
  u32 o0 = (u32)f2bf(a0) | ((u32)f2bf(a1) << 16);
  u32 o1 = (u32)f2bf(a2) | ((u32)f2bf(a3) << 16);
  *(uint2*)&ylat[(size_t)t * DL_ + c0] = make_uint2(o0, o1);
}

extern "C" void kernel_launch(void* const* d_in, const int* in_sizes, int n_in,
                              void* d_out, int out_size, void* d_ws, size_t ws_size,
                              hipStream_t stream) {
  (void)in_sizes; (void)n_in; (void)out_size;
  const float* x = (const float*)d_in[0];
  const float* gw = (const float*)d_in[1];
  const float* gbias = (const float*)d_in[2];
  const float* fc1 = (const float*)d_in[3];
  const float* fc2 = (const float*)d_in[4];
  const float* w1 = (const float*)d_in[5];
  const float* w2 = (const float*)d_in[6];
  const float* sw1 = (const float*)d_in[7];
  const float* sw2 = (const float*)d_in[8];
  float* out = (float*)d_out;

  char* ws = (char*)d_ws;
  size_t off = 0;
  auto alloc = [&](size_t bytes) {
    char* p = ws + off;
    off += (bytes + 255) & ~(size_t)255;
    return p;
  };
  float* logits = (float*)alloc((size_t)T_ * E_ * 4);
  int* cnts = (int*)alloc(E_ * 4);
  int* etok = (int*)alloc((size_t)E_ * CAP_ * 4);
  int* row_of = (int*)alloc((size_t)T_ * TOPK * 4);
  float* tww = (float*)alloc((size_t)T_ * TOPK * 4);
  u16* xl = (u16*)alloc((size_t)T_ * DL_ * 2);
  u16* ylat = (u16*)alloc((size_t)T_ * DL_ * 2);

  size_t big1_elems = (size_t)E_ * CAP_ * I_;
  if ((size_t)T_ * SI_ > big1_elems) big1_elems = (size_t)T_ * SI_;
  size_t need_fast = off + (((size_t)T_ * D_ * 2 + 255) & ~255ul)
                     + (((size_t)D_ * DL_ * 2 + 255) & ~255ul)
                     + ((big1_elems * 2 + 255) & ~255ul)
                     + (((size_t)E_ * CAP_ * DL_ * 2 + 255) & ~255ul)
                     + (((size_t)E_ * I_ * DL_ * 2 + 255) & ~255ul);

  hipMemsetAsync(cnts, 0, E_ * 4, stream);
  gate_logits_k<<<dim3(T_ / 16, 2), 256, 0, stream>>>(x, gw, logits);
  route_k<<<T_ / 4, 256, 0, stream>>>(logits, gbias, cnts, etok, row_of, tww);

  if (ws_size >= need_fast) {
    u16* xbf = (u16*)alloc((size_t)T_ * D_ * 2);
    u16* fc2b = (u16*)alloc((size_t)D_ * DL_ * 2);
    u16* big1 = (u16*)alloc(big1_elems * 2);
    u16* eoutB = (u16*)alloc((size_t)E_ * CAP_ * DL_ * 2);
    u16* wbuf = (u16*)alloc((size_t)E_ * I_ * DL_ * 2);
    u16* sw1b = wbuf;
    u16* sw2b = wbuf + (size_t)SI_ * D_;
    u16* fc1b = wbuf + 2 * (size_t)SI_ * D_;

    cvt_f2b_k<<<(T_ * D_ / 8 + 255) / 256, 256, 0, stream>>>(x, xbf, T_ * D_ / 8);
    cvt_f2b_k<<<(SI_ * D_ / 8 + 255) / 256, 256, 0, stream>>>(sw1, sw1b, SI_ * D_ / 8);
    cvt_f2b_k<<<(SI_ * D_ / 8 + 255) / 256, 256, 0, stream>>>(sw2, sw2b, SI_ * D_ / 8);
    cvt_f2b_k<<<(DL_ * D_ / 8 + 255) / 256, 256, 0, stream>>>(fc1, fc1b, DL_ * D_ / 8);
    cvt_f2b_k<<<(D_ * DL_ / 8 + 255) / 256, 256, 0, stream>>>(fc2, fc2b, D_ * DL_ / 8);

    // shared path: hs = relu2(x @ sw1^T); out = hs @ sw2^T
    gemm_bf<1, false, 128><<<dim3(SI_ / 128, T_ / BM, 1), 256, 0, stream>>>(
        xbf, sw1b, big1, T_, D_, D_, D_, SI_, 0, 0, 0, nullptr, nullptr);
    gemm_bf<2, false, 64><<<dim3(D_ / 64, T_ / BM, 1), 256, 0, stream>>>(
        big1, sw2b, out, T_, SI_, SI_, SI_, D_, 0, 0, 0, nullptr, nullptr);

    // latent projection: xl = x @ fc1^T
    gemm_bf<0, false, 64><<<dim3(DL_ / 64, T_ / BM, 1), 256, 0, stream>>>(
        xbf, fc1b, xl, T_, D_, D_, D_, DL_, 0, 0, 0, nullptr, nullptr);

    // expert FFN stage 1
    int nw = E_ * I_ * DL_ / 8;
    cvt_f2b_k<<<(nw + 255) / 256, 256, 0, stream>>>(w1, wbuf, nw);
    gemm_bf<1, true, 128><<<dim3(I_ / 128, CAP_ / BM, E_), 256, 0, stream>>>(
        xl, wbuf, big1, CAP_, DL_, DL_, DL_, I_,
        0, (long)I_ * DL_, (long)CAP_ * I_, cnts, etok);

    // expert FFN stage 2
    cvt_f2b_k<<<(nw + 255) / 256, 256, 0, stream>>>(w2, wbuf, nw);
    gemm_bf<0, false, 128><<<dim3(DL_ / 128, CAP_ / BM, E_), 256, 0, stream>>>(
        big1, wbuf, eoutB, CAP_, I_, I_, I_, DL_,
        (long)CAP_ * I_, (long)DL_ * I_, (long)CAP_ * DL_, cnts, nullptr);

    combine_k<<<T_, 256, 0, stream>>>(eoutB, row_of, tww, ylat);

    // out += ylat @ fc2^T
    gemm_bf<3, false, 64><<<dim3(D_ / 64, T_ / BM, 1), 256, 0, stream>>>(
        ylat, fc2b, out, T_, DL_, DL_, DL_, D_, 0, 0, 0, nullptr, nullptr);
  } else {
    char* big = alloc((size_t)E_ * CAP_ * I_ * 2 + (size_t)E_ * CAP_ * DL_ * 2);
    u16* hs = (u16*)big;
    u16* h = (u16*)big;
    u16* eoutB = (u16*)(big + (size_t)E_ * CAP_ * I_ * 2);

    gemm_nt<0, 1><<<dim3(SI_ / BNF, T_ / BM, 1), 256, 0, stream>>>(
        x, sw1, hs, T_, D_, D_, D_, SI_, 0, 0, 0, nullptr, nullptr);
    gemm_nt<1, 2><<<dim3(D_ / BNF, T_ / BM, 1), 256, 0, stream>>>(
        hs, sw2, out, T_, SI_, SI_, SI_, D_, 0, 0, 0, nullptr, nullptr);
    gemm_nt<0, 0><<<dim3(DL_ / BNF, T_ / BM, 1), 256, 0, stream>>>(
        x, fc1, xl, T_, D_, D_, D_, DL_, 0, 0, 0, nullptr, nullptr);
    gemm_nt<1, 1><<<dim3(I_ / BNF, CAP_ / BM, E_), 256, 0, stream>>>(
        xl, w1, h, CAP_, DL_, DL_, DL_, I_,
        0, (long)I_ * DL_, (long)CAP_ * I_, cnts, etok);
    gemm_nt<1, 0><<<dim3(DL_ / BNF, CAP_ / BM, E_), 256, 0, stream>>>(
        h, w2, eoutB, CAP_, I_, I_, I_, DL_,
        (long)CAP_ * I_, (long)DL_ * I_, (long)CAP_ * DL_, cnts, nullptr);
    combine_k<<<T_, 256, 0, stream>>>(eoutB, row_of, tww, ylat);
    gemm_nt<1, 3><<<dim3(D_ / BNF, T_ / BM, 1), 256, 0, stream>>>(
        ylat, fc2, out, T_, DL_, DL_, DL_, D_, 0, 0, 0, nullptr, nullptr);
  }
}